// Round 1
// baseline (158.749 us; speedup 1.0000x reference)
//
#include <hip/hip_runtime.h>

#define DIM    128
#define BATCH  16384
#define ALPHA  0.001f

// One block (256 threads, 4 waves) per batch element.
// Thread layout: row = tid>>1 (0..127), j-half = (tid&1)*64.
// Each thread: 16 float4 loads of R (contiguous 256B), dot with t (LDS),
// plus r^2 accumulation. Pair-combine with shfl_xor(1), then block reduce.
__global__ void __launch_bounds__(256) rescal_main_kernel(
    const int*   __restrict__ h_idx,
    const int*   __restrict__ r_idx,
    const int*   __restrict__ t_idx,
    const float* __restrict__ labels,
    const float* __restrict__ ent_w,
    const float* __restrict__ rel_w,
    float*       __restrict__ scores_out,   // d_out + 1
    float4*      __restrict__ partials)     // [BATCH] (err, r2, h2+t2, 0)
{
    const int b   = blockIdx.x;
    const int tid = threadIdx.x;

    __shared__ float t_lds[DIM];
    __shared__ float h_lds[DIM];
    __shared__ float red_s[4], red_r[4], red_h[4];

    const int hi = h_idx[b];
    const int ri = r_idx[b];
    const int ti = t_idx[b];

    if (tid < DIM) {
        t_lds[tid] = ent_w[(size_t)ti * DIM + tid];
        h_lds[tid] = ent_w[(size_t)hi * DIM + tid];
    }
    __syncthreads();

    const int row = tid >> 1;
    const int jh  = (tid & 1) << 6;   // 0 or 64
    const float4* __restrict__ rv =
        (const float4*)(rel_w + (size_t)ri * (DIM * DIM) + (size_t)row * DIM + jh);
    const float4* tv = (const float4*)(t_lds + jh);

    float acc = 0.f, r2 = 0.f;
    #pragma unroll
    for (int k = 0; k < 16; ++k) {
        float4 rr = rv[k];
        float4 tt = tv[k];
        acc += rr.x * tt.x + rr.y * tt.y + rr.z * tt.z + rr.w * tt.w;
        r2  += rr.x * rr.x + rr.y * rr.y + rr.z * rr.z + rr.w * rr.w;
    }

    // tr[row] = both halves combined (lanes tid, tid^1 are same wave)
    const float tr_i = acc + __shfl_xor(acc, 1);
    float sc = (tid & 1) ? 0.f : h_lds[row] * tr_i;

    // h^2 + t^2 contributions (256 threads cover 128 h + 128 t elements)
    float ht = (tid < DIM) ? h_lds[tid] * h_lds[tid]
                           : t_lds[tid - DIM] * t_lds[tid - DIM];

    // wave reduce (64 lanes)
    #pragma unroll
    for (int off = 32; off >= 1; off >>= 1) {
        sc += __shfl_down(sc, off);
        r2 += __shfl_down(r2, off);
        ht += __shfl_down(ht, off);
    }
    const int wave = tid >> 6;
    if ((tid & 63) == 0) { red_s[wave] = sc; red_r[wave] = r2; red_h[wave] = ht; }
    __syncthreads();

    if (tid == 0) {
        const float score = red_s[0] + red_s[1] + red_s[2] + red_s[3];
        const float r2t   = red_r[0] + red_r[1] + red_r[2] + red_r[3];
        const float htt   = red_h[0] + red_h[1] + red_h[2] + red_h[3];
        scores_out[b] = score;
        const float d = score - labels[b];
        partials[b] = make_float4(d * d, r2t, htt, 0.f);
    }
}

// Single-block deterministic final reduction -> loss at d_out[0].
__global__ void __launch_bounds__(256) rescal_final_kernel(
    const float4* __restrict__ partials,
    float*        __restrict__ loss_out)
{
    const int tid = threadIdx.x;
    float err = 0.f, r2 = 0.f, ht = 0.f;
    for (int k = tid; k < BATCH; k += 256) {
        const float4 p = partials[k];
        err += p.x; r2 += p.y; ht += p.z;
    }
    __shared__ float re[4], rr[4], rh[4];
    #pragma unroll
    for (int off = 32; off >= 1; off >>= 1) {
        err += __shfl_down(err, off);
        r2  += __shfl_down(r2, off);
        ht  += __shfl_down(ht, off);
    }
    const int wave = tid >> 6;
    if ((tid & 63) == 0) { re[wave] = err; rr[wave] = r2; rh[wave] = ht; }
    __syncthreads();
    if (tid == 0) {
        err = re[0] + re[1] + re[2] + re[3];
        r2  = rr[0] + rr[1] + rr[2] + rr[3];
        ht  = rh[0] + rh[1] + rh[2] + rh[3];
        const float mse   = err / (float)BATCH;
        const float norms = (ht / ((float)BATCH * DIM)
                           + r2 / ((float)BATCH * (float)(DIM * DIM))) / 3.0f;
        loss_out[0] = mse + ALPHA * norms;
    }
}

extern "C" void kernel_launch(void* const* d_in, const int* in_sizes, int n_in,
                              void* d_out, int out_size, void* d_ws, size_t ws_size,
                              hipStream_t stream) {
    const int*   h_idx  = (const int*)d_in[0];
    const int*   r_idx  = (const int*)d_in[1];
    const int*   t_idx  = (const int*)d_in[2];
    const float* labels = (const float*)d_in[3];
    const float* ent_w  = (const float*)d_in[4];
    const float* rel_w  = (const float*)d_in[5];

    float*  out      = (float*)d_out;       // [0]=loss, [1..BATCH]=scores
    float4* partials = (float4*)d_ws;       // BATCH * 16 bytes

    rescal_main_kernel<<<BATCH, 256, 0, stream>>>(
        h_idx, r_idx, t_idx, labels, ent_w, rel_w, out + 1, partials);
    rescal_final_kernel<<<1, 256, 0, stream>>>(partials, out);
}

// Round 2
// 138.349 us; speedup vs baseline: 1.1474x; 1.1474x over previous
//
#include <hip/hip_runtime.h>

#define DIM    128
#define BATCH  16384
#define RELN   500
#define ALPHA  0.001f

// ---------- prep: bucket batch elements by relation ----------

__global__ void __launch_bounds__(512) zero_counts_kernel(int* counts) {
    counts[threadIdx.x] = 0;   // 512 ints (>= RELN)
}

__global__ void __launch_bounds__(256) hist_kernel(const int* __restrict__ r_idx,
                                                   int* __restrict__ counts) {
    const int i = blockIdx.x * 256 + threadIdx.x;
    atomicAdd(&counts[r_idx[i]], 1);
}

__global__ void __launch_bounds__(512) scan_kernel(const int* __restrict__ counts,
                                                   int* __restrict__ offsets,
                                                   int* __restrict__ cursor) {
    __shared__ int s[512];
    const int tid = threadIdx.x;
    const int v = (tid < RELN) ? counts[tid] : 0;
    s[tid] = v;
    __syncthreads();
    for (int d = 1; d < 512; d <<= 1) {
        const int x = (tid >= d) ? s[tid - d] : 0;
        __syncthreads();
        s[tid] += x;
        __syncthreads();
    }
    const int incl = s[tid];
    if (tid < RELN) { offsets[tid] = incl - v; cursor[tid] = incl - v; }
    if (tid == RELN - 1) offsets[RELN] = incl;   // = BATCH
}

__global__ void __launch_bounds__(256) scatter_kernel(const int* __restrict__ r_idx,
                                                      int* __restrict__ cursor,
                                                      int* __restrict__ bucket) {
    const int i = blockIdx.x * 256 + threadIdx.x;
    const int pos = atomicAdd(&cursor[r_idx[i]], 1);
    bucket[pos] = i;
}

// ---------- main: one block per relation, R held in registers ----------
// Thread owns row = tid>>1, col-half jh = (tid&1)*64 of R (16 float4 regs).
// Chunks of 8 batch elements: t,h staged in LDS; t reads are 2-addr/wave
// broadcasts (conflict-free). Per-element (err, h2+t2) written to partials[b]
// so the final reduction order is fixed -> bit-deterministic outputs.

__global__ void __launch_bounds__(256) rescal_rel_kernel(
    const int*   __restrict__ bucket,
    const int*   __restrict__ offsets,
    const int*   __restrict__ h_idx,
    const int*   __restrict__ t_idx,
    const float* __restrict__ labels,
    const float* __restrict__ ent_w,
    const float* __restrict__ rel_w,
    float*       __restrict__ scores_out,   // d_out + 1
    float2*      __restrict__ partials,     // [BATCH] (err, h2+t2)
    float*       __restrict__ r2norm)       // [RELN] count * ||R||^2
{
    const int rel  = blockIdx.x;
    const int tid  = threadIdx.x;
    const int base = offsets[rel];
    const int n    = offsets[rel + 1] - base;

    const int row = tid >> 1;
    const int jh  = (tid & 1) << 6;

    // load R tile into registers + ||R||^2 partial
    float4 rr[16];
    const float4* rv = (const float4*)(rel_w + (size_t)rel * (DIM * DIM)
                                             + (size_t)row * DIM + jh);
    float r2 = 0.f;
    #pragma unroll
    for (int k = 0; k < 16; ++k) {
        rr[k] = rv[k];
        r2 += rr[k].x * rr[k].x + rr[k].y * rr[k].y
            + rr[k].z * rr[k].z + rr[k].w * rr[k].w;
    }

    __shared__ float t_lds[8][DIM];
    __shared__ float h_lds[8][DIM];
    __shared__ float red[4][8];
    __shared__ float ht_red[8];
    __shared__ int   bidx[8];
    __shared__ float r2_red[4];

    #pragma unroll
    for (int off = 32; off >= 1; off >>= 1) r2 += __shfl_xor(r2, off);
    if ((tid & 63) == 0) r2_red[tid >> 6] = r2;
    __syncthreads();
    if (tid == 0)
        r2norm[rel] = (float)n * (r2_red[0] + r2_red[1] + r2_red[2] + r2_red[3]);

    const int eg  = tid >> 5;          // element slot 0..7
    const int col = (tid & 31) << 2;   // 0..124

    for (int c = 0; c < n; c += 8) {
        const int e_cnt = (n - c < 8) ? (n - c) : 8;

        float4 tv4 = make_float4(0.f, 0.f, 0.f, 0.f);
        float4 hv4 = make_float4(0.f, 0.f, 0.f, 0.f);
        int b = -1;
        if (eg < e_cnt) {
            b   = bucket[base + c + eg];
            tv4 = *(const float4*)(ent_w + (size_t)t_idx[b] * DIM + col);
            hv4 = *(const float4*)(ent_w + (size_t)h_idx[b] * DIM + col);
        }
        *(float4*)&t_lds[eg][col] = tv4;
        *(float4*)&h_lds[eg][col] = hv4;
        if ((tid & 31) == 0) bidx[eg] = b;

        float htp = tv4.x*tv4.x + tv4.y*tv4.y + tv4.z*tv4.z + tv4.w*tv4.w
                  + hv4.x*hv4.x + hv4.y*hv4.y + hv4.z*hv4.z + hv4.w*hv4.w;
        #pragma unroll
        for (int off = 16; off >= 1; off >>= 1) htp += __shfl_xor(htp, off);
        if ((tid & 31) == 0) ht_red[eg] = htp;
        __syncthreads();

        // 8 matvec partials per thread, R from registers (reused 8x)
        float acc[8];
        #pragma unroll
        for (int e = 0; e < 8; ++e) acc[e] = 0.f;
        #pragma unroll
        for (int k = 0; k < 16; ++k) {
            const float4 r4 = rr[k];
            #pragma unroll
            for (int e = 0; e < 8; ++e) {
                const float4 t4 = *(const float4*)&t_lds[e][jh + (k << 2)];
                acc[e] += r4.x * t4.x + r4.y * t4.y + r4.z * t4.z + r4.w * t4.w;
            }
        }

        #pragma unroll
        for (int e = 0; e < 8; ++e) {
            float v = acc[e] + __shfl_xor(acc[e], 1);   // full row-dot, both lanes
            v = (tid & 1) ? 0.f : h_lds[e][row] * v;
            #pragma unroll
            for (int off = 2; off <= 32; off <<= 1) v += __shfl_xor(v, off);
            if ((tid & 63) == 0) red[tid >> 6][e] = v;
        }
        __syncthreads();

        if (tid < e_cnt) {
            const float s  = red[0][tid] + red[1][tid] + red[2][tid] + red[3][tid];
            const int   bb = bidx[tid];
            scores_out[bb] = s;
            const float d  = s - labels[bb];
            partials[bb] = make_float2(d * d, ht_red[tid]);
        }
        __syncthreads();
    }
}

// ---------- final: fixed-order reduction -> loss ----------

__global__ void __launch_bounds__(512) final_kernel(
    const float2* __restrict__ partials,
    const float*  __restrict__ r2norm,
    float*        __restrict__ loss_out)
{
    const int tid = threadIdx.x;
    float err = 0.f, ht = 0.f, r2 = 0.f;
    for (int i = tid; i < BATCH; i += 512) {
        const float2 p = partials[i];
        err += p.x; ht += p.y;
    }
    for (int i = tid; i < RELN; i += 512) r2 += r2norm[i];

    __shared__ float re[8], rh[8], rr2[8];
    #pragma unroll
    for (int off = 32; off >= 1; off >>= 1) {
        err += __shfl_down(err, off);
        ht  += __shfl_down(ht, off);
        r2  += __shfl_down(r2, off);
    }
    if ((tid & 63) == 0) { const int w = tid >> 6; re[w] = err; rh[w] = ht; rr2[w] = r2; }
    __syncthreads();
    if (tid == 0) {
        err = 0.f; ht = 0.f; r2 = 0.f;
        for (int w = 0; w < 8; ++w) { err += re[w]; ht += rh[w]; r2 += rr2[w]; }
        const float mse   = err / (float)BATCH;
        const float norms = (ht / ((float)BATCH * DIM)
                           + r2 / ((float)BATCH * (float)(DIM * DIM))) / 3.0f;
        loss_out[0] = mse + ALPHA * norms;
    }
}

extern "C" void kernel_launch(void* const* d_in, const int* in_sizes, int n_in,
                              void* d_out, int out_size, void* d_ws, size_t ws_size,
                              hipStream_t stream) {
    const int*   h_idx  = (const int*)d_in[0];
    const int*   r_idx  = (const int*)d_in[1];
    const int*   t_idx  = (const int*)d_in[2];
    const float* labels = (const float*)d_in[3];
    const float* ent_w  = (const float*)d_in[4];
    const float* rel_w  = (const float*)d_in[5];

    float* out = (float*)d_out;   // [0]=loss, [1..BATCH]=scores

    // workspace layout (<= ~205 KB)
    float2* partials = (float2*)d_ws;                         // BATCH * 8 B
    int*    bucket   = (int*)((char*)d_ws + BATCH * 8);       // BATCH * 4 B
    int*    counts   = bucket + BATCH;                        // 512 ints
    int*    offsets  = counts + 512;                          // 512 ints (uses RELN+1)
    int*    cursor   = offsets + 512;                         // 512 ints
    float*  r2norm   = (float*)(cursor + 512);                // RELN floats

    zero_counts_kernel<<<1, 512, 0, stream>>>(counts);
    hist_kernel<<<BATCH / 256, 256, 0, stream>>>(r_idx, counts);
    scan_kernel<<<1, 512, 0, stream>>>(counts, offsets, cursor);
    scatter_kernel<<<BATCH / 256, 256, 0, stream>>>(r_idx, cursor, bucket);
    rescal_rel_kernel<<<RELN, 256, 0, stream>>>(
        bucket, offsets, h_idx, t_idx, labels, ent_w, rel_w,
        out + 1, partials, r2norm);
    final_kernel<<<1, 512, 0, stream>>>(partials, r2norm, out);
}

// Round 3
// 74.805 us; speedup vs baseline: 2.1222x; 1.8495x over previous
//
#include <hip/hip_runtime.h>

#define DIM       128
#define BATCH     16384
#define RELN      500
#define ALPHA     0.001f
#define CHUNK     8
#define MAXCHUNKS 4096
#define MAIN_GRID 2048

// ---------- prep ----------

__global__ void __launch_bounds__(256) hist_kernel(const int* __restrict__ r_idx,
                                                   int* __restrict__ counts) {
    const int i = blockIdx.x * 256 + threadIdx.x;
    atomicAdd(&counts[r_idx[i]], 1);
}

// Single block: scan counts -> offsets/cursor, then scan ceil(n/8) -> chunk list.
__global__ void __launch_bounds__(512) scan_kernel(const int* __restrict__ counts,
                                                   int* __restrict__ offsets,
                                                   int* __restrict__ cursor,
                                                   int2* __restrict__ chunk_desc,
                                                   int* __restrict__ n_chunks) {
    __shared__ int s[512];
    const int tid = threadIdx.x;
    const int v = (tid < RELN) ? counts[tid] : 0;
    s[tid] = v;
    __syncthreads();
    for (int d = 1; d < 512; d <<= 1) {
        const int x = (tid >= d) ? s[tid - d] : 0;
        __syncthreads();
        s[tid] += x;
        __syncthreads();
    }
    const int my_off = s[tid] - v;
    if (tid < RELN) { offsets[tid] = my_off; cursor[tid] = my_off; }
    if (tid == RELN - 1) offsets[RELN] = s[tid];
    __syncthreads();

    const int nc = (tid < RELN) ? ((v + CHUNK - 1) / CHUNK) : 0;
    s[tid] = nc;
    __syncthreads();
    for (int d = 1; d < 512; d <<= 1) {
        const int x = (tid >= d) ? s[tid - d] : 0;
        __syncthreads();
        s[tid] += x;
        __syncthreads();
    }
    const int cbase = s[tid] - nc;
    if (tid == 511) n_chunks[0] = s[511];
    for (int i = 0; i < nc; ++i)
        chunk_desc[cbase + i] = make_int2(tid, my_off + i * CHUNK);
}

__global__ void __launch_bounds__(256) scatter_kernel(const int* __restrict__ r_idx,
                                                      int* __restrict__ cursor,
                                                      int* __restrict__ bucket) {
    const int i = blockIdx.x * 256 + threadIdx.x;
    const int pos = atomicAdd(&cursor[r_idx[i]], 1);
    bucket[pos] = i;
}

// ---------- main: grid-stride over chunks; R in regs, 16 rows x 4 cols per thread ----------
// Wave w owns rows [32w, 32w+32). Thread (w, lane l): rows 32w+2p+(l>>5), p=0..15,
// float4 cols [4*(l&31), +4). R load = 16 perfectly coalesced 1KB wave-loads.
// One t4 LDS read per element feeds 16 row-FMAs (64 scalar FMAs); h applied via
// 2-address broadcast reads. Reduction tree is slot-invariant -> deterministic.

__global__ void __launch_bounds__(256, 4) rescal_chunk_kernel(
    const int2*  __restrict__ chunk_desc,
    const int*   __restrict__ n_chunks,
    const int*   __restrict__ offsets,
    const int*   __restrict__ bucket,
    const int*   __restrict__ h_idx,
    const int*   __restrict__ t_idx,
    const float* __restrict__ labels,
    const float* __restrict__ ent_w,
    const float* __restrict__ rel_w,
    float*       __restrict__ scores_out,   // d_out + 1
    float2*      __restrict__ partials,     // [BATCH] (err, h2+t2)
    float*       __restrict__ chunk_r2)     // [MAXCHUNKS] e_cnt * ||R||^2
{
    const int tid = threadIdx.x;
    const int w   = tid >> 6;
    const int l   = tid & 63;
    const int hi  = l >> 5;          // 0/1
    const int c4  = l & 31;          // float4 col index
    const int total = n_chunks[0];

    __shared__ float t_lds[CHUNK][DIM];
    __shared__ float h_lds[CHUNK][DIM];
    __shared__ float red[4][CHUNK];
    __shared__ float ht_red[CHUNK];
    __shared__ int   bidx[CHUNK];
    __shared__ float r2_red[4];

    const int eg   = tid >> 5;       // staging element slot 0..7
    const int col4 = tid & 31;

    for (int cid = blockIdx.x; cid < total; cid += MAIN_GRID) {
        const int2 cd   = chunk_desc[cid];
        const int rel   = cd.x;
        const int start = cd.y;
        const int e_cnt = min(CHUNK, offsets[rel + 1] - start);

        // ---- load R tile into registers (+ ||R||^2 partial) ----
        float4 rr[16];
        const float* Rbase = rel_w + (size_t)rel * (DIM * DIM);
        float r2 = 0.f;
        #pragma unroll
        for (int p = 0; p < 16; ++p) {
            rr[p] = *(const float4*)(Rbase + (size_t)(32 * w + 2 * p + hi) * DIM + c4 * 4);
            r2 += rr[p].x * rr[p].x + rr[p].y * rr[p].y
                + rr[p].z * rr[p].z + rr[p].w * rr[p].w;
        }
        #pragma unroll
        for (int off = 32; off >= 1; off >>= 1) r2 += __shfl_xor(r2, off);
        if (l == 0) r2_red[w] = r2;

        // ---- stage t, h for up to 8 elements ----
        float4 tv4 = make_float4(0.f, 0.f, 0.f, 0.f);
        float4 hv4 = make_float4(0.f, 0.f, 0.f, 0.f);
        int b = -1;
        if (eg < e_cnt) {
            b   = bucket[start + eg];
            tv4 = *(const float4*)(ent_w + (size_t)t_idx[b] * DIM + col4 * 4);
            hv4 = *(const float4*)(ent_w + (size_t)h_idx[b] * DIM + col4 * 4);
        }
        *(float4*)&t_lds[eg][col4 * 4] = tv4;
        *(float4*)&h_lds[eg][col4 * 4] = hv4;

        float htp = tv4.x*tv4.x + tv4.y*tv4.y + tv4.z*tv4.z + tv4.w*tv4.w
                  + hv4.x*hv4.x + hv4.y*hv4.y + hv4.z*hv4.z + hv4.w*hv4.w;
        #pragma unroll
        for (int off = 16; off >= 1; off >>= 1) htp += __shfl_xor(htp, off);
        if ((tid & 31) == 0) { ht_red[eg] = htp; bidx[eg] = b; }
        __syncthreads();

        if (tid == 0)
            chunk_r2[cid] = (float)e_cnt *
                (r2_red[0] + r2_red[1] + r2_red[2] + r2_red[3]);

        // ---- compute: per element, 1 t4 read -> 16 rows, h via broadcast ----
        #pragma unroll
        for (int e = 0; e < CHUNK; ++e) {
            const float4 t4 = *(const float4*)&t_lds[e][c4 * 4];
            float acc = 0.f;
            #pragma unroll
            for (int p = 0; p < 16; ++p) {
                const float d = rr[p].x * t4.x + rr[p].y * t4.y
                              + rr[p].z * t4.z + rr[p].w * t4.w;
                acc += h_lds[e][32 * w + 2 * p + hi] * d;
            }
            #pragma unroll
            for (int off = 32; off >= 1; off >>= 1) acc += __shfl_xor(acc, off);
            if (l == 0) red[w][e] = acc;
        }
        __syncthreads();

        if (tid < e_cnt) {
            const float s  = red[0][tid] + red[1][tid] + red[2][tid] + red[3][tid];
            const int   bb = bidx[tid];
            scores_out[bb] = s;
            const float d  = s - labels[bb];
            partials[bb] = make_float2(d * d, ht_red[tid]);
        }
        __syncthreads();   // protect LDS reuse next iteration
    }
}

// ---------- final: fixed-order reduction -> loss ----------

__global__ void __launch_bounds__(512) final_kernel(
    const float2* __restrict__ partials,
    const float*  __restrict__ chunk_r2,
    const int*    __restrict__ n_chunks,
    float*        __restrict__ loss_out)
{
    const int tid = threadIdx.x;
    const int total = n_chunks[0];
    float err = 0.f, ht = 0.f, r2 = 0.f;
    for (int i = tid; i < BATCH; i += 512) {
        const float2 p = partials[i];
        err += p.x; ht += p.y;
    }
    for (int i = tid; i < total; i += 512) r2 += chunk_r2[i];

    __shared__ float re[8], rh[8], rr2[8];
    #pragma unroll
    for (int off = 32; off >= 1; off >>= 1) {
        err += __shfl_down(err, off);
        ht  += __shfl_down(ht, off);
        r2  += __shfl_down(r2, off);
    }
    if ((tid & 63) == 0) { const int v = tid >> 6; re[v] = err; rh[v] = ht; rr2[v] = r2; }
    __syncthreads();
    if (tid == 0) {
        err = 0.f; ht = 0.f; r2 = 0.f;
        for (int v = 0; v < 8; ++v) { err += re[v]; ht += rh[v]; r2 += rr2[v]; }
        const float mse   = err / (float)BATCH;
        const float norms = (ht / ((float)BATCH * DIM)
                           + r2 / ((float)BATCH * (float)(DIM * DIM))) / 3.0f;
        loss_out[0] = mse + ALPHA * norms;
    }
}

extern "C" void kernel_launch(void* const* d_in, const int* in_sizes, int n_in,
                              void* d_out, int out_size, void* d_ws, size_t ws_size,
                              hipStream_t stream) {
    const int*   h_idx  = (const int*)d_in[0];
    const int*   r_idx  = (const int*)d_in[1];
    const int*   t_idx  = (const int*)d_in[2];
    const float* labels = (const float*)d_in[3];
    const float* ent_w  = (const float*)d_in[4];
    const float* rel_w  = (const float*)d_in[5];

    float* out = (float*)d_out;   // [0]=loss, [1..BATCH]=scores

    // workspace layout (~252 KB)
    char* ws = (char*)d_ws;
    float2* partials   = (float2*)ws;                       ws += BATCH * sizeof(float2);
    int*    bucket     = (int*)ws;                          ws += BATCH * sizeof(int);
    int*    counts     = (int*)ws;                          ws += 512 * sizeof(int);
    int*    offsets    = (int*)ws;                          ws += 512 * sizeof(int);
    int*    cursor     = (int*)ws;                          ws += 512 * sizeof(int);
    int2*   chunk_desc = (int2*)ws;                         ws += MAXCHUNKS * sizeof(int2);
    float*  chunk_r2   = (float*)ws;                        ws += MAXCHUNKS * sizeof(float);
    int*    n_chunks   = (int*)ws;

    hipMemsetAsync(counts, 0, 512 * sizeof(int), stream);
    hist_kernel<<<BATCH / 256, 256, 0, stream>>>(r_idx, counts);
    scan_kernel<<<1, 512, 0, stream>>>(counts, offsets, cursor, chunk_desc, n_chunks);
    scatter_kernel<<<BATCH / 256, 256, 0, stream>>>(r_idx, cursor, bucket);
    rescal_chunk_kernel<<<MAIN_GRID, 256, 0, stream>>>(
        chunk_desc, n_chunks, offsets, bucket, h_idx, t_idx,
        labels, ent_w, rel_w, out + 1, partials, chunk_r2);
    final_kernel<<<1, 512, 0, stream>>>(partials, chunk_r2, n_chunks, out);
}